// Round 1
// baseline (1249.637 us; speedup 1.0000x reference)
//
#include <hip/hip_runtime.h>

// ---------------------------------------------------------------------------
// Decoder: out = (tanh(x @ (s1*tern(w1-n1)) + b1)) @ (s2*tern(w2-n2)) + b2
// B=4096, D_IN=1024, D_H=16384, D_OUT=3072
//
// Round-3: GEMM1 computes h^T tiles via swapped MFMA operands
// (mfma(w1_frag, x_frag)), so the accumulator layout natively matches the
// fragment-major chunk format GEMM2 consumes (m across lanes, k2 across
// regs). Epilogue packs reg-pairs to u32, stages 32 KB chunk image in LDS,
// streams out coalesced uint4 — replaces 64 scattered 2-byte global stores
// per thread.
//
// Chunk format (8192 B = one 128(m|n) x 32(k) bf16 tile):
//   elem(s, h, lane, e) = T[m = s*32 + (lane&31)][k = h*16 + (lane>>5)*8 + e]
//   flat elem offset = s*1024 + h*512 + lane*8 + e   (s=0..3, h=0..1)
// This is exactly the 32x32x16 MFMA A/B operand order, so fragment reads are
// ds_read_b128 at subtile_base + lane*16 (zero bank conflicts) and staging is
// global_load_lds(16B) with the required uniform+lane*16 LDS dst.
// ---------------------------------------------------------------------------

typedef __bf16 bf16x8 __attribute__((ext_vector_type(8)));
typedef float f32x16 __attribute__((ext_vector_type(16)));

#define AS1 __attribute__((address_space(1)))
#define AS3 __attribute__((address_space(3)))

__device__ __forceinline__ void gload_lds16(const void* g, void* l) {
    __builtin_amdgcn_global_load_lds((AS1 const void*)g, (AS3 void*)l, 16, 0, 0);
}

__device__ __forceinline__ unsigned short f2bf(float f) {
    union { float f; unsigned int u; } v; v.f = f;
    unsigned int u = v.u;
    unsigned int r = u + 0x7fffu + ((u >> 16) & 1u);
    return (unsigned short)(r >> 16);
}

__device__ __forceinline__ unsigned short tern_bf(float q) {
    return (q > 1.f) ? 0x3F80u : ((q < -1.f) ? 0xBF80u : 0u);
}

// scale arrives as a 1-element array; python int -> int32, but be robust to
// a float32 as well.
__device__ __forceinline__ float load_scale(const void* p) {
    int i = *(const int*)p;
    if (i >= -1000000 && i <= 1000000) return (float)i;
    union { int i; float f; } v; v.i = i; return v.f;
}

__device__ __forceinline__ float tanh_fast(float x) {
    float e = __expf(2.0f * x);                       // v_exp_f32 based
    return 1.0f - 2.0f * __builtin_amdgcn_rcpf(e + 1.0f);
}

// ---------------------------------------------------------------------------
// pack_x: x[4096][1024] fp32 -> chunks [mt=32][kt=32][8192B fragment-major]
// grid (32 kt, 32 mt), block 256. Reads 32B granules (row-scattered, only
// 24 MB total), writes 16B coalesced.
// ---------------------------------------------------------------------------
__global__ __launch_bounds__(256) void pack_x_kernel(
    const float* __restrict__ x, unsigned short* __restrict__ out)
{
    const int kt = blockIdx.x, mt = blockIdx.y, tid = threadIdx.x;
    unsigned short* chunk = out + (size_t)(mt * 32 + kt) * 4096;
#pragma unroll
    for (int it = 0; it < 2; it++) {
        int g = tid + it * 256;
        int s = g >> 7, r = g & 127, h = (r >> 6) & 1, ln = r & 63;
        int m = s * 32 + (ln & 31), k = h * 16 + (ln >> 5) * 8;
        const float* src = x + (size_t)(mt * 128 + m) * 1024 + kt * 32 + k;
        float4 v0 = *(const float4*)src;
        float4 v1 = *(const float4*)(src + 4);
        unsigned int w0 = (unsigned int)f2bf(v0.x) | ((unsigned int)f2bf(v0.y) << 16);
        unsigned int w1 = (unsigned int)f2bf(v0.z) | ((unsigned int)f2bf(v0.w) << 16);
        unsigned int w2 = (unsigned int)f2bf(v1.x) | ((unsigned int)f2bf(v1.y) << 16);
        unsigned int w3 = (unsigned int)f2bf(v1.z) | ((unsigned int)f2bf(v1.w) << 16);
        uint4 o; o.x = w0; o.y = w1; o.z = w2; o.w = w3;
        *(uint4*)&chunk[(size_t)g * 8] = o;
    }
}

// ---------------------------------------------------------------------------
// quant_pack_w: w,n [K][N] fp32 -> tern bf16 chunks [N/128][K/32][8192B]
// float4 coalesced reads, LDS transpose (stride 34: write 4-way, read 2-way
// conflicts), 16B coalesced packed stores. grid (K/32, N/128), block 256
// ---------------------------------------------------------------------------
__global__ __launch_bounds__(256) void quant_pack_w(
    const float* __restrict__ w, const float* __restrict__ nz,
    const void* __restrict__ scale_ptr,
    unsigned short* __restrict__ out, int N, int Kt)
{
    __shared__ unsigned short lt[128 * 34];
    const int kt = blockIdx.x, nt = blockIdx.y, tid = threadIdx.x;
    const float scale = load_scale(scale_ptr);
#pragma unroll
    for (int it = 0; it < 4; it++) {
        int p = it * 1024 + tid * 4;
        int kr = p >> 7, nc = p & 127;
        size_t g = (size_t)(kt * 32 + kr) * N + nt * 128 + nc;
        float4 wv = *(const float4*)(w + g);
        float4 nv = *(const float4*)(nz + g);
        lt[(nc + 0) * 34 + kr] = tern_bf(wv.x - scale * nv.x);
        lt[(nc + 1) * 34 + kr] = tern_bf(wv.y - scale * nv.y);
        lt[(nc + 2) * 34 + kr] = tern_bf(wv.z - scale * nv.z);
        lt[(nc + 3) * 34 + kr] = tern_bf(wv.w - scale * nv.w);
    }
    __syncthreads();
    unsigned short* chunk = out + (size_t)(nt * Kt + kt) * 4096;
#pragma unroll
    for (int it = 0; it < 2; it++) {
        int g = tid + it * 256;
        int s = g >> 7, r = g & 127, h = (r >> 6) & 1, ln = r & 63;
        int n = s * 32 + (ln & 31), k = h * 16 + (ln >> 5) * 8;
        const unsigned int* p32 = (const unsigned int*)&lt[n * 34 + k];
        uint4 o; o.x = p32[0]; o.y = p32[1]; o.z = p32[2]; o.w = p32[3];
        *(uint4*)&chunk[(size_t)g * 8] = o;
    }
}

// ---------------------------------------------------------------------------
// GEMM core: 128x128 tile, BK=32, 4 waves (2x2), each wave 2x2 MFMA
// 32x32x16_bf16 tiles (64x64 per wave).
// ---------------------------------------------------------------------------

// GEMM1 (swapped): computes h^T tiles: acc[i][j] = mfma(w1_frag[i], x_frag[j])
// => C[row = n1 (D_H)][col = m (batch)], col = lane&31, row over regs.
// This is exactly the chunk format's per-lane layout for GEMM2's A operand,
// so the epilogue is: tanh -> pack reg pairs -> u32 LDS chunk image ->
// coalesced uint4 global stores. No scattered 2-byte global stores.
__global__ __launch_bounds__(256) void gemm1_kernel(
    const unsigned short* __restrict__ Ap,   // xq   [mt=32][kt=32] chunks
    const unsigned short* __restrict__ Bp,   // w1 tern [nt=128][kt=32] chunks
    unsigned short* __restrict__ Hq,
    const float* __restrict__ s1, const float* __restrict__ b1,
    int Kt)
{
    // stage: 32 KB chunk image for epilogue; first 16 KB aliases As/Bs
    __shared__ unsigned short stage[16384];
    unsigned short* const As = stage;            // 4096 ushorts (8 KB)
    unsigned short* const Bs = stage + 4096;     // 4096 ushorts (8 KB)
    const int tid = threadIdx.x;
    const int nt = blockIdx.x, mt = blockIdx.y;  // nt: D_H/128, mt: B/128
    const int lane = tid & 63, wave = tid >> 6;
    const int wm = (wave & 1) * 64;              // batch-col offset (x side)
    const int wn = (wave >> 1) * 64;             // n1-row offset (w1 side)

    f32x16 acc[2][2] = {};

    const unsigned short* Ab = Ap + (size_t)mt * Kt * 4096;
    const unsigned short* Bb = Bp + (size_t)nt * Kt * 4096;

    for (int kt = 0; kt < Kt; ++kt) {
        const unsigned short* Ac = Ab + kt * 4096;
        const unsigned short* Bc = Bb + kt * 4096;
        gload_lds16(Ac + tid * 8,        &As[tid * 8]);
        gload_lds16(Ac + 2048 + tid * 8, &As[2048 + tid * 8]);
        gload_lds16(Bc + tid * 8,        &Bs[tid * 8]);
        gload_lds16(Bc + 2048 + tid * 8, &Bs[2048 + tid * 8]);
        __syncthreads();

        bf16x8 af[2][2], bg[2][2];
#pragma unroll
        for (int h = 0; h < 2; h++)
#pragma unroll
            for (int i = 0; i < 2; i++) {
                af[i][h] = *(const bf16x8*)&As[((wm >> 5) + i) * 1024 + h * 512 + lane * 8];
                bg[i][h] = *(const bf16x8*)&Bs[((wn >> 5) + i) * 1024 + h * 512 + lane * 8];
            }
        // SWAPPED operand order: A = w1 fragment (rows n1), B = x fragment
        // (cols m). acc[i][j]: rows wn+i*32+rowfn(reg,hi), cols wm+j*32+(lane&31)
#pragma unroll
        for (int h = 0; h < 2; h++)
#pragma unroll
            for (int i = 0; i < 2; i++)
#pragma unroll
                for (int j = 0; j < 2; j++)
                    acc[i][j] = __builtin_amdgcn_mfma_f32_32x32x16_bf16(
                        bg[i][h], af[j][h], acc[i][j], 0, 0, 0);
        __syncthreads();
    }

    // Epilogue: t = tanh(s1[n1]*acc + b1[n1]); pack reg pairs (consecutive
    // k2 per lane) into u32; write 32 KB chunk image (4 chunks) to LDS;
    // stream out coalesced.
    const int mloc = lane & 31;
    const int hi = lane >> 5;
    unsigned int* stg32 = (unsigned int*)stage;
#pragma unroll
    for (int i = 0; i < 2; i++) {
        const int cLocal = (wn >> 5) + i;            // which chunk (0..3)
        const int n1i = nt * 128 + wn + i * 32;      // global n1 base of subtile
#pragma unroll
        for (int j = 0; j < 2; j++) {
            const int s = (wm >> 5) + j;             // m-subtile within chunk
#pragma unroll
            for (int c = 0; c < 8; c++) {
                // regs 2c,2c+1 hold rows n1off, n1off+1 (consecutive k2)
                const int n1off = 8 * (c >> 1) + 4 * hi + 2 * (c & 1);
                const int n1g = n1i + n1off;
                float t0 = tanh_fast(s1[n1g] * acc[i][j][2 * c] + b1[n1g]);
                float t1 = tanh_fast(s1[n1g + 1] * acc[i][j][2 * c + 1] + b1[n1g + 1]);
                unsigned int pw = (unsigned int)f2bf(t0)
                                | ((unsigned int)f2bf(t1) << 16);
                // chunk u32 addr: s*512 + h*256 + hi'*128 + mloc*4 + 2*hi + (c&1)
                // h = (c>>2)&1, hi' = (c>>1)&1
                const int a32 = cLocal * 2048 + s * 512
                              + ((c >> 2) & 1) * 256 + ((c >> 1) & 1) * 128
                              + mloc * 4 + 2 * hi + (c & 1);
                stg32[a32] = pw;
            }
        }
    }
    __syncthreads();

    // copy 4 contiguous chunks (32 KB) to hq, fully coalesced
    uint4* dst = (uint4*)(Hq + (size_t)(mt * 512 + nt * 4) * 4096);
    const uint4* srcv = (const uint4*)stage;
#pragma unroll
    for (int t = 0; t < 8; t++)
        dst[t * 256 + tid] = srcv[t * 256 + tid];
}

// GEMM2: out[m][n] = s2[n]*acc + b2[n], fp32 row-major [4096][3072]
__global__ __launch_bounds__(256) void gemm2_kernel(
    const unsigned short* __restrict__ Ap,   // hq
    const unsigned short* __restrict__ Bp,   // w2 tern
    float* __restrict__ out,
    const float* __restrict__ s2, const float* __restrict__ b2,
    int Kt)
{
    __shared__ unsigned short As[4096];
    __shared__ unsigned short Bs[4096];
    const int tid = threadIdx.x;
    const int nt = blockIdx.x, mt = blockIdx.y;
    const int lane = tid & 63, wave = tid >> 6;
    const int wm = (wave >> 1) * 64, wn = (wave & 1) * 64;

    f32x16 acc[2][2] = {};

    const unsigned short* Ab = Ap + (size_t)mt * Kt * 4096;
    const unsigned short* Bb = Bp + (size_t)nt * Kt * 4096;

    for (int kt = 0; kt < Kt; ++kt) {
        const unsigned short* Ac = Ab + kt * 4096;
        const unsigned short* Bc = Bb + kt * 4096;
        gload_lds16(Ac + tid * 8,        &As[tid * 8]);
        gload_lds16(Ac + 2048 + tid * 8, &As[2048 + tid * 8]);
        gload_lds16(Bc + tid * 8,        &Bs[tid * 8]);
        gload_lds16(Bc + 2048 + tid * 8, &Bs[2048 + tid * 8]);
        __syncthreads();

        bf16x8 af[2][2], bg[2][2];
#pragma unroll
        for (int h = 0; h < 2; h++)
#pragma unroll
            for (int i = 0; i < 2; i++) {
                af[i][h] = *(const bf16x8*)&As[((wm >> 5) + i) * 1024 + h * 512 + lane * 8];
                bg[i][h] = *(const bf16x8*)&Bs[((wn >> 5) + i) * 1024 + h * 512 + lane * 8];
            }
#pragma unroll
        for (int h = 0; h < 2; h++)
#pragma unroll
            for (int i = 0; i < 2; i++)
#pragma unroll
                for (int j = 0; j < 2; j++)
                    acc[i][j] = __builtin_amdgcn_mfma_f32_32x32x16_bf16(
                        af[i][h], bg[j][h], acc[i][j], 0, 0, 0);
        __syncthreads();
    }

    const int l31 = lane & 31;
    const int rowbase = 4 * (lane >> 5);
#pragma unroll
    for (int j = 0; j < 2; j++) {
        int n = nt * 128 + wn + j * 32 + l31;
        float sc = s2[n], bb = b2[n];
#pragma unroll
        for (int i = 0; i < 2; i++) {
#pragma unroll
            for (int reg = 0; reg < 16; reg++) {
                int m = mt * 128 + wm + i * 32 + (reg & 3) + 8 * (reg >> 2) + rowbase;
                out[(size_t)m * 3072 + n] = sc * acc[i][j][reg] + bb;
            }
        }
    }
}

// ---------------------------------------------------------------------------
extern "C" void kernel_launch(void* const* d_in, const int* in_sizes, int n_in,
                              void* d_out, int out_size, void* d_ws, size_t ws_size,
                              hipStream_t stream) {
    const float* x  = (const float*)d_in[0];   // [4096,1024]
    const float* w1 = (const float*)d_in[1];   // [1024,16384]
    const float* s1 = (const float*)d_in[2];   // [16384]
    const float* b1 = (const float*)d_in[3];   // [16384]
    const float* w2 = (const float*)d_in[4];   // [16384,3072]
    const float* s2 = (const float*)d_in[5];   // [3072]
    const float* b2 = (const float*)d_in[6];   // [3072]
    const float* n1 = (const float*)d_in[7];   // [1024,16384]
    const float* n2 = (const float*)d_in[8];   // [16384,3072]
    const void* scale_p = d_in[9];             // scalar
    float* out = (float*)d_out;

    // workspace layout (MiB offsets): xq 8 | w1q 32 | hq 128 | w2q 96 = 264
    if (ws_size < (264ull << 20)) return;
    unsigned char* ws = (unsigned char*)d_ws;
    unsigned short* xq  = (unsigned short*)(ws);
    unsigned short* w1q = (unsigned short*)(ws + (8ull << 20));
    unsigned short* hq  = (unsigned short*)(ws + (40ull << 20));
    unsigned short* w2q = (unsigned short*)(ws + (168ull << 20));

    // pack/quant
    pack_x_kernel<<<dim3(32, 32), 256, 0, stream>>>(x, xq);
    quant_pack_w<<<dim3(32, 128), 256, 0, stream>>>(w1, n1, scale_p, w1q, 16384, 32);
    quant_pack_w<<<dim3(512, 24), 256, 0, stream>>>(w2, n2, scale_p, w2q, 3072, 512);

    // GEMM1 (swapped): [16384x1024 w1^T] @ [1024x4096 x^T] -> hq packed bf16
    gemm1_kernel<<<dim3(128, 32), 256, 0, stream>>>(xq, w1q, hq, s1, b1, 32);
    // GEMM2: [4096x16384] @ [16384x3072] -> out fp32
    gemm2_kernel<<<dim3(24, 32), 256, 0, stream>>>(hq, w2q, out, s2, b2, 512);
}

// Round 2
// 1089.066 us; speedup vs baseline: 1.1474x; 1.1474x over previous
//
#include <hip/hip_runtime.h>

// ---------------------------------------------------------------------------
// Decoder: out = (tanh(x @ (s1*tern(w1-n1)) + b1)) @ (s2*tern(w2-n2)) + b2
// B=4096, D_IN=1024, D_H=16384, D_OUT=3072
//
// Round-4: gemm1 reverted to round-0 (the 32KB-LDS epilogue variant measured
// +52us). gemm2 rewritten as 256x256 8-phase-style pipelined kernel:
// BK=64, 512 thr / 8 waves, double-buffered half-tile LDS (128 KB),
// counted vmcnt(4) (never 0 in the main loop), raw s_barrier, setprio
// around MFMA clusters. Fragment-major chunks keep all LDS traffic
// conflict-free and global_load_lds linear.
//
// Chunk format (8192 B = one 128(m|n) x 32(k) bf16 tile):
//   elem(s, h, lane, e) = T[m = s*32 + (lane&31)][k = h*16 + (lane>>5)*8 + e]
//   flat elem offset = s*1024 + h*512 + lane*8 + e   (s=0..3, h=0..1)
// ---------------------------------------------------------------------------

typedef __bf16 bf16x8 __attribute__((ext_vector_type(8)));
typedef float f32x16 __attribute__((ext_vector_type(16)));

#define AS1 __attribute__((address_space(1)))
#define AS3 __attribute__((address_space(3)))

__device__ __forceinline__ void gload_lds16(const void* g, void* l) {
    __builtin_amdgcn_global_load_lds((AS1 const void*)g, (AS3 void*)l, 16, 0, 0);
}

__device__ __forceinline__ unsigned short f2bf(float f) {
    union { float f; unsigned int u; } v; v.f = f;
    unsigned int u = v.u;
    unsigned int r = u + 0x7fffu + ((u >> 16) & 1u);
    return (unsigned short)(r >> 16);
}

__device__ __forceinline__ unsigned short tern_bf(float q) {
    return (q > 1.f) ? 0x3F80u : ((q < -1.f) ? 0xBF80u : 0u);
}

__device__ __forceinline__ float load_scale(const void* p) {
    int i = *(const int*)p;
    if (i >= -1000000 && i <= 1000000) return (float)i;
    union { int i; float f; } v; v.i = i; return v.f;
}

__device__ __forceinline__ float tanh_fast(float x) {
    float e = __expf(2.0f * x);
    return 1.0f - 2.0f * __builtin_amdgcn_rcpf(e + 1.0f);
}

// ---------------------------------------------------------------------------
// pack_x: x[4096][1024] fp32 -> chunks [mt=32][kt=32][8192B fragment-major]
// ---------------------------------------------------------------------------
__global__ __launch_bounds__(256) void pack_x_kernel(
    const float* __restrict__ x, unsigned short* __restrict__ out)
{
    const int kt = blockIdx.x, mt = blockIdx.y, tid = threadIdx.x;
    unsigned short* chunk = out + (size_t)(mt * 32 + kt) * 4096;
#pragma unroll
    for (int it = 0; it < 2; it++) {
        int g = tid + it * 256;
        int s = g >> 7, r = g & 127, h = (r >> 6) & 1, ln = r & 63;
        int m = s * 32 + (ln & 31), k = h * 16 + (ln >> 5) * 8;
        const float* src = x + (size_t)(mt * 128 + m) * 1024 + kt * 32 + k;
        float4 v0 = *(const float4*)src;
        float4 v1 = *(const float4*)(src + 4);
        unsigned int w0 = (unsigned int)f2bf(v0.x) | ((unsigned int)f2bf(v0.y) << 16);
        unsigned int w1 = (unsigned int)f2bf(v0.z) | ((unsigned int)f2bf(v0.w) << 16);
        unsigned int w2 = (unsigned int)f2bf(v1.x) | ((unsigned int)f2bf(v1.y) << 16);
        unsigned int w3 = (unsigned int)f2bf(v1.z) | ((unsigned int)f2bf(v1.w) << 16);
        uint4 o; o.x = w0; o.y = w1; o.z = w2; o.w = w3;
        *(uint4*)&chunk[(size_t)g * 8] = o;
    }
}

// ---------------------------------------------------------------------------
// quant_pack_w: w,n [K][N] fp32 -> tern bf16 chunks [N/128][K/32][8192B]
// ---------------------------------------------------------------------------
__global__ __launch_bounds__(256) void quant_pack_w(
    const float* __restrict__ w, const float* __restrict__ nz,
    const void* __restrict__ scale_ptr,
    unsigned short* __restrict__ out, int N, int Kt)
{
    __shared__ unsigned short lt[128 * 34];
    const int kt = blockIdx.x, nt = blockIdx.y, tid = threadIdx.x;
    const float scale = load_scale(scale_ptr);
#pragma unroll
    for (int it = 0; it < 4; it++) {
        int p = it * 1024 + tid * 4;
        int kr = p >> 7, nc = p & 127;
        size_t g = (size_t)(kt * 32 + kr) * N + nt * 128 + nc;
        float4 wv = *(const float4*)(w + g);
        float4 nv = *(const float4*)(nz + g);
        lt[(nc + 0) * 34 + kr] = tern_bf(wv.x - scale * nv.x);
        lt[(nc + 1) * 34 + kr] = tern_bf(wv.y - scale * nv.y);
        lt[(nc + 2) * 34 + kr] = tern_bf(wv.z - scale * nv.z);
        lt[(nc + 3) * 34 + kr] = tern_bf(wv.w - scale * nv.w);
    }
    __syncthreads();
    unsigned short* chunk = out + (size_t)(nt * Kt + kt) * 4096;
#pragma unroll
    for (int it = 0; it < 2; it++) {
        int g = tid + it * 256;
        int s = g >> 7, r = g & 127, h = (r >> 6) & 1, ln = r & 63;
        int n = s * 32 + (ln & 31), k = h * 16 + (ln >> 5) * 8;
        const unsigned int* p32 = (const unsigned int*)&lt[n * 34 + k];
        uint4 o; o.x = p32[0]; o.y = p32[1]; o.z = p32[2]; o.w = p32[3];
        *(uint4*)&chunk[(size_t)g * 8] = o;
    }
}

// ---------------------------------------------------------------------------
// GEMM1 (round-0 version): 128x128 tile, BK=32, 4 waves (2x2), each wave
// 2x2 MFMA 32x32x16_bf16 tiles. h = tanh(s1[n]*acc + b1[n]) written bf16
// into GEMM2's packed-A chunks [mt=32][k2t=512][8192B fragment-major].
// ---------------------------------------------------------------------------
__global__ __launch_bounds__(256) void gemm1_kernel(
    const unsigned short* __restrict__ Ap,   // xq
    const unsigned short* __restrict__ Bp,   // w1 tern
    unsigned short* __restrict__ Hq,
    const float* __restrict__ s1, const float* __restrict__ b1,
    int Kt)
{
    __shared__ unsigned short As[4096];
    __shared__ unsigned short Bs[4096];
    const int tid = threadIdx.x;
    const int nt = blockIdx.x, mt = blockIdx.y;
    const int lane = tid & 63, wave = tid >> 6;
    const int wm = (wave >> 1) * 64, wn = (wave & 1) * 64;

    f32x16 acc[2][2] = {};

    const unsigned short* Ab = Ap + (size_t)mt * Kt * 4096;
    const unsigned short* Bb = Bp + (size_t)nt * Kt * 4096;

    for (int kt = 0; kt < Kt; ++kt) {
        const unsigned short* Ac = Ab + kt * 4096;
        const unsigned short* Bc = Bb + kt * 4096;
        gload_lds16(Ac + tid * 8,        &As[tid * 8]);
        gload_lds16(Ac + 2048 + tid * 8, &As[2048 + tid * 8]);
        gload_lds16(Bc + tid * 8,        &Bs[tid * 8]);
        gload_lds16(Bc + 2048 + tid * 8, &Bs[2048 + tid * 8]);
        __syncthreads();

        bf16x8 af[2][2], bg[2][2];
#pragma unroll
        for (int h = 0; h < 2; h++)
#pragma unroll
            for (int i = 0; i < 2; i++) {
                af[i][h] = *(const bf16x8*)&As[((wm >> 5) + i) * 1024 + h * 512 + lane * 8];
                bg[i][h] = *(const bf16x8*)&Bs[((wn >> 5) + i) * 1024 + h * 512 + lane * 8];
            }
#pragma unroll
        for (int h = 0; h < 2; h++)
#pragma unroll
            for (int i = 0; i < 2; i++)
#pragma unroll
                for (int j = 0; j < 2; j++)
                    acc[i][j] = __builtin_amdgcn_mfma_f32_32x32x16_bf16(
                        af[i][h], bg[j][h], acc[i][j], 0, 0, 0);
        __syncthreads();
    }

    // epilogue: tanh(s1*acc+b1) -> fragment-major bf16 chunks for GEMM2
    const int l31 = lane & 31;
    const int hsel = (lane >> 4) & 1;      // (k_local>>4)
    const int b32sel = (lane >> 3) & 1;    // which 8-elem group within half
    const int e = lane & 7;
    const int rowbase = 4 * (lane >> 5);
#pragma unroll
    for (int j = 0; j < 2; j++) {
        int k2g = nt * 128 + wn + j * 32 + l31;
        float sc = s1[k2g], bb = b1[k2g];
        size_t ct = (size_t)mt * 512 + nt * 4 + (wn >> 5) + j;
        unsigned short* chunk = Hq + ct * 4096;
#pragma unroll
        for (int i = 0; i < 2; i++) {
            int sbase = ((wm >> 5) + i) * 1024 + hsel * 512 + b32sel * 256 + e;
#pragma unroll
            for (int reg = 0; reg < 16; reg++) {
                int row = (reg & 3) + 8 * (reg >> 2) + rowbase;
                float v = tanh_fast(sc * acc[i][j][reg] + bb);
                chunk[sbase + row * 8] = f2bf(v);
            }
        }
    }
}

// ---------------------------------------------------------------------------
// GEMM2: 256x256 tile, BK=64, 512 thr / 8 waves (2M x 4N), pipelined
// 4-phase K-step with counted vmcnt + raw barriers + setprio.
// Each wave: 128(M) x 64(N) = acc[4][2] of 32x32 tiles.
//   m-frag i: rows (i>>1)*128 + wm + (i&1)*32,  wm = ((wave>>2)&1)*64
//   n-frag j: cols j*128 + (wave&3)*32
// LDS: lds[dbuf 2][half 4][8192 ushorts]; halves: 0=A rows0-127, 1=A rows
// 128-255, 2=B cols0-127, 3=B cols128-255. Each half = 2 chunks (16 KB),
// contiguous in global (chunk row stride 512 chunks).
// Phase p of step t computes one acc-quadrant over all 4 k-slices:
//   ph0: acc[0..1][0] (A0,B0)  ph1: acc[0..1][1] (A0,B1)
//   ph2: acc[2..3][1] (A1,B1)  ph3: acc[2..3][0] (A1,B0)
// Stage schedule (during step t for step t+1): ph0->A0, ph1->B0, ph2->B1,
// ph3->A1. vmcnt(4) at ph0/ph1/ph3 forces exactly the half-tile needed by
// the next phase while keeping 2-3 half-tiles in flight (never vmcnt(0)).
// ---------------------------------------------------------------------------

#define VMCNT(n) asm volatile("s_waitcnt vmcnt(" #n ")" ::: "memory")
#define BARRIER() { asm volatile("" ::: "memory"); __builtin_amdgcn_s_barrier(); asm volatile("" ::: "memory"); }

#define RD_FRAG(dst, HALF, SUB, P)                                            \
    dst[0] = *(const bf16x8*)&lds[P][HALF][(SUB)*1024 + lane*8];              \
    dst[1] = *(const bf16x8*)&lds[P][HALF][(SUB)*1024 + 512 + lane*8];        \
    dst[2] = *(const bf16x8*)&lds[P][HALF][4096 + (SUB)*1024 + lane*8];       \
    dst[3] = *(const bf16x8*)&lds[P][HALF][4096 + (SUB)*1024 + 512 + lane*8];

#define MFMA4(ci, cj, av, bv)                                                 \
    acc[ci][cj] = __builtin_amdgcn_mfma_f32_32x32x16_bf16(av[0], bv[0], acc[ci][cj], 0,0,0); \
    acc[ci][cj] = __builtin_amdgcn_mfma_f32_32x32x16_bf16(av[1], bv[1], acc[ci][cj], 0,0,0); \
    acc[ci][cj] = __builtin_amdgcn_mfma_f32_32x32x16_bf16(av[2], bv[2], acc[ci][cj], 0,0,0); \
    acc[ci][cj] = __builtin_amdgcn_mfma_f32_32x32x16_bf16(av[3], bv[3], acc[ci][cj], 0,0,0);

#define GSTEP(P, Q, T, W0, W1, DO_STAGE, LAST)                                \
  { /* ---- ph0: A0 x B0 -> acc[0..1][0] ---- */                              \
    RD_FRAG(a0, 0, sA, P); RD_FRAG(a1, 0, sA + 1, P);                         \
    RD_FRAG(b0, 2, sB, P);                                                    \
    if (DO_STAGE) STAGE(Q, 0, (T) + 1);                                       \
    W0; BARRIER();                                                            \
    __builtin_amdgcn_s_setprio(1);                                            \
    MFMA4(0, 0, a0, b0); MFMA4(1, 0, a1, b0);                                 \
    __builtin_amdgcn_s_setprio(0);                                            \
    BARRIER();                                                                \
    /* ---- ph1: A0 x B1 -> acc[0..1][1] ---- */                              \
    RD_FRAG(b1, 3, sB, P);                                                    \
    if (DO_STAGE) STAGE(Q, 2, (T) + 1);                                       \
    W1; BARRIER();                                                            \
    __builtin_amdgcn_s_setprio(1);                                            \
    MFMA4(0, 1, a0, b1); MFMA4(1, 1, a1, b1);                                 \
    __builtin_amdgcn_s_setprio(0);                                            \
    BARRIER();                                                                \
    /* ---- ph2: A1 x B1 -> acc[2..3][1] ---- */                              \
    RD_FRAG(a0, 1, sA, P); RD_FRAG(a1, 1, sA + 1, P);                         \
    if (DO_STAGE) STAGE(Q, 3, (T) + 1);                                       \
    BARRIER();                                                                \
    __builtin_amdgcn_s_setprio(1);                                            \
    MFMA4(2, 1, a0, b1); MFMA4(3, 1, a1, b1);                                 \
    __builtin_amdgcn_s_setprio(0);                                            \
    BARRIER();                                                                \
    /* ---- ph3: A1 x B0 -> acc[2..3][0] ---- */                              \
    if (DO_STAGE) STAGE(Q, 1, (T) + 1);                                       \
    if (!(LAST)) { VMCNT(4); }                                                \
    BARRIER();                                                                \
    __builtin_amdgcn_s_setprio(1);                                            \
    MFMA4(2, 0, a0, b0); MFMA4(3, 0, a1, b0);                                 \
    __builtin_amdgcn_s_setprio(0);                                            \
    BARRIER();                                                                \
  }

__global__ __launch_bounds__(512, 2) void gemm2_256_kernel(
    const unsigned short* __restrict__ Ap,   // hq  chunks [mt128][k2t=512]
    const unsigned short* __restrict__ Bp,   // w2q chunks [nt128][k2t=512]
    float* __restrict__ out,
    const float* __restrict__ s2, const float* __restrict__ b2,
    int nstep)                                // K / 64 = 256
{
    __shared__ unsigned short lds[2][4][8192];   // 128 KiB
    const int tid = threadIdx.x;
    const int lane = tid & 63, wave = tid >> 6;
    const int NT = blockIdx.x, MT = blockIdx.y;
    const int wm = ((wave >> 2) & 1) * 64;
    const int sA = wm >> 5;          // 0 or 2
    const int sB = wave & 3;

    f32x16 acc[4][2] = {};

    const unsigned short* Ab = Ap + ((size_t)(2 * MT) * 512) * 4096;
    const unsigned short* Bb = Bp + ((size_t)(2 * NT) * 512) * 4096;

    // stage half-tile `half` of K-step `t` into dbuf `q`.
    // half: 0=A0,1=A1 (chunk rows 2MT+half), 2=B0,3=B1 (rows 2NT+half-2).
    // 16 KB = 2 contiguous chunks; 2 x global_load_lds_dwordx4 per thread.
    auto STAGE = [&](int q, int half, int t) {
        const unsigned short* g = (half < 2)
            ? (Ab + ((size_t)(half * 512 + 2 * t)) * 4096)
            : (Bb + ((size_t)((half - 2) * 512 + 2 * t)) * 4096);
        unsigned short* l = &lds[q][half][0];
        gload_lds16(g + tid * 8,        l + tid * 8);
        gload_lds16(g + 4096 + tid * 8, l + 4096 + tid * 8);
    };

    bf16x8 a0[4], a1[4], b0[4], b1[4];

    // prologue: stage all 4 half-tiles of step 0 (issue order = steady order)
    STAGE(0, 0, 0); STAGE(0, 2, 0); STAGE(0, 3, 0); STAGE(0, 1, 0);
    VMCNT(4);       // forces A0(0), B0(0); leaves B1,A1 in flight
    BARRIER();

    for (int t = 0; t < nstep - 2; t += 2) {
        GSTEP(0, 1, t,     VMCNT(4), VMCNT(4), true, false);
        GSTEP(1, 0, t + 1, VMCNT(4), VMCNT(4), true, false);
    }
    GSTEP(0, 1, nstep - 2, VMCNT(4), VMCNT(4), true,  false);
    GSTEP(1, 0, nstep - 1, VMCNT(2), VMCNT(0), false, true);

    // epilogue: out[m][n] = s2[n]*acc + b2[n]
    const int l31 = lane & 31;
    const int rowb = 4 * (lane >> 5);
#pragma unroll
    for (int j = 0; j < 2; j++) {
        int n = NT * 256 + j * 128 + sB * 32 + l31;
        float sc = s2[n], bb = b2[n];
#pragma unroll
        for (int i = 0; i < 4; i++) {
            int mbase = MT * 256 + (i >> 1) * 128 + wm + (i & 1) * 32;
#pragma unroll
            for (int reg = 0; reg < 16; reg++) {
                int m = mbase + (reg & 3) + 8 * (reg >> 2) + rowb;
                out[(size_t)m * 3072 + n] = sc * acc[i][j][reg] + bb;
            }
        }
    }
}

// ---------------------------------------------------------------------------
extern "C" void kernel_launch(void* const* d_in, const int* in_sizes, int n_in,
                              void* d_out, int out_size, void* d_ws, size_t ws_size,
                              hipStream_t stream) {
    const float* x  = (const float*)d_in[0];   // [4096,1024]
    const float* w1 = (const float*)d_in[1];   // [1024,16384]
    const float* s1 = (const float*)d_in[2];   // [16384]
    const float* b1 = (const float*)d_in[3];   // [16384]
    const float* w2 = (const float*)d_in[4];   // [16384,3072]
    const float* s2 = (const float*)d_in[5];   // [3072]
    const float* b2 = (const float*)d_in[6];   // [3072]
    const float* n1 = (const float*)d_in[7];   // [1024,16384]
    const float* n2 = (const float*)d_in[8];   // [16384,3072]
    const void* scale_p = d_in[9];             // scalar
    float* out = (float*)d_out;

    // workspace layout (MiB offsets): xq 8 | w1q 32 | hq 128 | w2q 96 = 264
    if (ws_size < (264ull << 20)) return;
    unsigned char* ws = (unsigned char*)d_ws;
    unsigned short* xq  = (unsigned short*)(ws);
    unsigned short* w1q = (unsigned short*)(ws + (8ull << 20));
    unsigned short* hq  = (unsigned short*)(ws + (40ull << 20));
    unsigned short* w2q = (unsigned short*)(ws + (168ull << 20));

    // pack/quant
    pack_x_kernel<<<dim3(32, 32), 256, 0, stream>>>(x, xq);
    quant_pack_w<<<dim3(32, 128), 256, 0, stream>>>(w1, n1, scale_p, w1q, 16384, 32);
    quant_pack_w<<<dim3(512, 24), 256, 0, stream>>>(w2, n2, scale_p, w2q, 3072, 512);

    // GEMM1: [4096x1024] @ [1024x16384] -> hq (packed bf16, fused tanh)
    gemm1_kernel<<<dim3(128, 32), 256, 0, stream>>>(xq, w1q, hq, s1, b1, 32);
    // GEMM2: [4096x16384] @ [16384x3072] -> out fp32, 256^2 pipelined
    gemm2_256_kernel<<<dim3(12, 16), 512, 0, stream>>>(hq, w2q, out, s2, b2, 256);
}

// Round 5
// 1056.571 us; speedup vs baseline: 1.1827x; 1.0308x over previous
//
#include <hip/hip_runtime.h>

// ---------------------------------------------------------------------------
// Decoder: out = (tanh(x @ (s1*tern(w1-n1)) + b1)) @ (s2*tern(w2-n2)) + b2
// B=4096, D_IN=1024, D_H=16384, D_OUT=3072
//
// Round-7 (round-6 stream-out fix): gemm1 on the verified 256x256 4-phase
// pipelined template (swapped operands: A=w1q, B=xq -> acc = h^T, natively
// in hq chunk layout). Fix: epilogue stream-out copies the FULL 64 KB per
// m-group (8 iters, src offset mg*4096 uint4); round-6 wrote only half of
// hq (absmax 5.4).
//
// Chunk format (8192 B = one 128(m|n) x 32(k) bf16 tile):
//   elem(s, h, lane, e) = T[m = s*32 + (lane&31)][k = h*16 + (lane>>5)*8 + e]
//   flat elem offset = s*1024 + h*512 + lane*8 + e   (s=0..3, h=0..1)
// ---------------------------------------------------------------------------

typedef __bf16 bf16x8 __attribute__((ext_vector_type(8)));
typedef float f32x16 __attribute__((ext_vector_type(16)));

#define AS1 __attribute__((address_space(1)))
#define AS3 __attribute__((address_space(3)))

__device__ __forceinline__ void gload_lds16(const void* g, void* l) {
    __builtin_amdgcn_global_load_lds((AS1 const void*)g, (AS3 void*)l, 16, 0, 0);
}

__device__ __forceinline__ unsigned short f2bf(float f) {
    union { float f; unsigned int u; } v; v.f = f;
    unsigned int u = v.u;
    unsigned int r = u + 0x7fffu + ((u >> 16) & 1u);
    return (unsigned short)(r >> 16);
}

__device__ __forceinline__ unsigned short tern_bf(float q) {
    return (q > 1.f) ? 0x3F80u : ((q < -1.f) ? 0xBF80u : 0u);
}

__device__ __forceinline__ float load_scale(const void* p) {
    int i = *(const int*)p;
    if (i >= -1000000 && i <= 1000000) return (float)i;
    union { int i; float f; } v; v.i = i; return v.f;
}

__device__ __forceinline__ float tanh_fast(float x) {
    float e = __expf(2.0f * x);
    return 1.0f - 2.0f * __builtin_amdgcn_rcpf(e + 1.0f);
}

// ---------------------------------------------------------------------------
// pack_x: x[4096][1024] fp32 -> chunks [mt=32][kt=32][8192B fragment-major]
// ---------------------------------------------------------------------------
__global__ __launch_bounds__(256) void pack_x_kernel(
    const float* __restrict__ x, unsigned short* __restrict__ out)
{
    const int kt = blockIdx.x, mt = blockIdx.y, tid = threadIdx.x;
    unsigned short* chunk = out + (size_t)(mt * 32 + kt) * 4096;
#pragma unroll
    for (int it = 0; it < 2; it++) {
        int g = tid + it * 256;
        int s = g >> 7, r = g & 127, h = (r >> 6) & 1, ln = r & 63;
        int m = s * 32 + (ln & 31), k = h * 16 + (ln >> 5) * 8;
        const float* src = x + (size_t)(mt * 128 + m) * 1024 + kt * 32 + k;
        float4 v0 = *(const float4*)src;
        float4 v1 = *(const float4*)(src + 4);
        unsigned int w0 = (unsigned int)f2bf(v0.x) | ((unsigned int)f2bf(v0.y) << 16);
        unsigned int w1 = (unsigned int)f2bf(v0.z) | ((unsigned int)f2bf(v0.w) << 16);
        unsigned int w2 = (unsigned int)f2bf(v1.x) | ((unsigned int)f2bf(v1.y) << 16);
        unsigned int w3 = (unsigned int)f2bf(v1.z) | ((unsigned int)f2bf(v1.w) << 16);
        uint4 o; o.x = w0; o.y = w1; o.z = w2; o.w = w3;
        *(uint4*)&chunk[(size_t)g * 8] = o;
    }
}

// ---------------------------------------------------------------------------
// quant_pack_w: w,n [K][N] fp32 -> tern bf16 chunks [N/128][K/32][8192B]
// ---------------------------------------------------------------------------
__global__ __launch_bounds__(256) void quant_pack_w(
    const float* __restrict__ w, const float* __restrict__ nz,
    const void* __restrict__ scale_ptr,
    unsigned short* __restrict__ out, int N, int Kt)
{
    __shared__ unsigned short lt[128 * 34];
    const int kt = blockIdx.x, nt = blockIdx.y, tid = threadIdx.x;
    const float scale = load_scale(scale_ptr);
#pragma unroll
    for (int it = 0; it < 4; it++) {
        int p = it * 1024 + tid * 4;
        int kr = p >> 7, nc = p & 127;
        size_t g = (size_t)(kt * 32 + kr) * N + nt * 128 + nc;
        float4 wv = *(const float4*)(w + g);
        float4 nv = *(const float4*)(nz + g);
        lt[(nc + 0) * 34 + kr] = tern_bf(wv.x - scale * nv.x);
        lt[(nc + 1) * 34 + kr] = tern_bf(wv.y - scale * nv.y);
        lt[(nc + 2) * 34 + kr] = tern_bf(wv.z - scale * nv.z);
        lt[(nc + 3) * 34 + kr] = tern_bf(wv.w - scale * nv.w);
    }
    __syncthreads();
    unsigned short* chunk = out + (size_t)(nt * Kt + kt) * 4096;
#pragma unroll
    for (int it = 0; it < 2; it++) {
        int g = tid + it * 256;
        int s = g >> 7, r = g & 127, h = (r >> 6) & 1, ln = r & 63;
        int n = s * 32 + (ln & 31), k = h * 16 + (ln >> 5) * 8;
        const unsigned int* p32 = (const unsigned int*)&lt[n * 34 + k];
        uint4 o; o.x = p32[0]; o.y = p32[1]; o.z = p32[2]; o.w = p32[3];
        *(uint4*)&chunk[(size_t)g * 8] = o;
    }
}

// ---------------------------------------------------------------------------
// 256x256 4-phase pipelined GEMM template pieces (verified round-2).
// 8 waves (2 x 4): wm = ((wave>>2)&1)*64, sB = wave&3.
// Wave output: 128(rows) x 64(cols) = acc[4][2] of 32x32 tiles:
//   row-frag i: (i>>1)*128 + wm + (i&1)*32 ; col-frag j: j*128 + sB*32
// LDS lds[dbuf2][half4][8192 u16]: 0=A rows0-127, 1=A rows128-255,
// 2=B cols0-127, 3=B cols128-255. Phases/K-step (BK=64):
//   ph0 A0xB0->acc[0..1][0] (stage A0'); ph1 A0xB1->acc[0..1][1] (stage B0')
//   ph2 A1xB1->acc[2..3][1] (stage B1'); ph3 A1xB0->acc[2..3][0] (stage A1')
// vmcnt counts individual loads (2 per half-tile); never drained to 0 in
// the main loop.
// ---------------------------------------------------------------------------

#define VMCNT(n) asm volatile("s_waitcnt vmcnt(" #n ")" ::: "memory")
#define BARRIER() { asm volatile("" ::: "memory"); __builtin_amdgcn_s_barrier(); asm volatile("" ::: "memory"); }

#define RD_FRAG(dst, HALF, SUB, P)                                            \
    dst[0] = *(const bf16x8*)&lds[P][HALF][(SUB)*1024 + lane*8];              \
    dst[1] = *(const bf16x8*)&lds[P][HALF][(SUB)*1024 + 512 + lane*8];        \
    dst[2] = *(const bf16x8*)&lds[P][HALF][4096 + (SUB)*1024 + lane*8];       \
    dst[3] = *(const bf16x8*)&lds[P][HALF][4096 + (SUB)*1024 + 512 + lane*8];

#define MFMA4(ci, cj, av, bv)                                                 \
    acc[ci][cj] = __builtin_amdgcn_mfma_f32_32x32x16_bf16(av[0], bv[0], acc[ci][cj], 0,0,0); \
    acc[ci][cj] = __builtin_amdgcn_mfma_f32_32x32x16_bf16(av[1], bv[1], acc[ci][cj], 0,0,0); \
    acc[ci][cj] = __builtin_amdgcn_mfma_f32_32x32x16_bf16(av[2], bv[2], acc[ci][cj], 0,0,0); \
    acc[ci][cj] = __builtin_amdgcn_mfma_f32_32x32x16_bf16(av[3], bv[3], acc[ci][cj], 0,0,0);

#define GSTEP(P, Q, T, W0, W1, DO_STAGE, LAST)                                \
  { /* ---- ph0: A0 x B0 -> acc[0..1][0] ---- */                              \
    RD_FRAG(fa0, 0, sA, P); RD_FRAG(fa1, 0, sA + 1, P);                       \
    RD_FRAG(fb0, 2, sB, P);                                                   \
    if (DO_STAGE) STAGE(Q, 0, (T) + 1);                                       \
    W0; BARRIER();                                                            \
    __builtin_amdgcn_s_setprio(1);                                            \
    MFMA4(0, 0, fa0, fb0); MFMA4(1, 0, fa1, fb0);                             \
    __builtin_amdgcn_s_setprio(0);                                            \
    BARRIER();                                                                \
    /* ---- ph1: A0 x B1 -> acc[0..1][1] ---- */                              \
    RD_FRAG(fb1, 3, sB, P);                                                   \
    if (DO_STAGE) STAGE(Q, 2, (T) + 1);                                       \
    W1; BARRIER();                                                            \
    __builtin_amdgcn_s_setprio(1);                                            \
    MFMA4(0, 1, fa0, fb1); MFMA4(1, 1, fa1, fb1);                             \
    __builtin_amdgcn_s_setprio(0);                                            \
    BARRIER();                                                                \
    /* ---- ph2: A1 x B1 -> acc[2..3][1] ---- */                              \
    RD_FRAG(fa0, 1, sA, P); RD_FRAG(fa1, 1, sA + 1, P);                       \
    if (DO_STAGE) STAGE(Q, 3, (T) + 1);                                       \
    BARRIER();                                                                \
    __builtin_amdgcn_s_setprio(1);                                            \
    MFMA4(2, 1, fa0, fb1); MFMA4(3, 1, fa1, fb1);                             \
    __builtin_amdgcn_s_setprio(0);                                            \
    BARRIER();                                                                \
    /* ---- ph3: A1 x B0 -> acc[2..3][0] ---- */                              \
    if (DO_STAGE) STAGE(Q, 1, (T) + 1);                                       \
    if (!(LAST)) { VMCNT(4); }                                                \
    BARRIER();                                                                \
    __builtin_amdgcn_s_setprio(1);                                            \
    MFMA4(2, 0, fa0, fb0); MFMA4(3, 0, fa1, fb0);                             \
    __builtin_amdgcn_s_setprio(0);                                            \
    BARRIER();                                                                \
  }

// ---------------------------------------------------------------------------
// GEMM1 (256^2, swapped): A = w1q (n1/k2 dim), B = xq (batch m dim).
// acc = h^T: k2 over regs, m over lanes == hq chunk layout.
// Grid (NT=16 batch, MT=64 n1) = 1024 blocks. K=1024 -> nstep=16.
// Epilogue: tanh -> u32 pack -> 128KB LDS chunk image -> coalesced stream.
// ---------------------------------------------------------------------------
__global__ __launch_bounds__(512, 2) void gemm1_256_kernel(
    const unsigned short* __restrict__ Ap,   // w1q chunks [(n1>>7)][kt=32]
    const unsigned short* __restrict__ Bp,   // xq  chunks [(m>>7)][kt=32]
    unsigned short* __restrict__ Hq,
    const float* __restrict__ s1v, const float* __restrict__ b1v)
{
    __shared__ unsigned short lds[2][4][8192];   // 128 KiB
    const int tid = threadIdx.x;
    const int lane = tid & 63, wave = tid >> 6;
    const int NT = blockIdx.x;     // batch / 256
    const int MT = blockIdx.y;     // n1 / 256
    const int wm = ((wave >> 2) & 1) * 64;
    const int sA = wm >> 5;
    const int sB = wave & 3;

    f32x16 acc[4][2] = {};

    const unsigned short* Ab = Ap + ((size_t)(2 * MT) * 32) * 4096;
    const unsigned short* Bb = Bp + ((size_t)(2 * NT) * 32) * 4096;

    auto STAGE = [&](int q, int half, int t) {
        const unsigned short* g = (half < 2)
            ? (Ab + ((size_t)(half * 32 + 2 * t)) * 4096)
            : (Bb + ((size_t)((half - 2) * 32 + 2 * t)) * 4096);
        unsigned short* l = &lds[q][half][0];
        gload_lds16(g + tid * 8,        l + tid * 8);
        gload_lds16(g + 4096 + tid * 8, l + 4096 + tid * 8);
    };

    bf16x8 fa0[4], fa1[4], fb0[4], fb1[4];

    STAGE(0, 0, 0); STAGE(0, 2, 0); STAGE(0, 3, 0); STAGE(0, 1, 0);
    VMCNT(4);
    BARRIER();

    for (int t = 0; t < 14; t += 2) {
        GSTEP(0, 1, t,     VMCNT(4), VMCNT(4), true, false);
        GSTEP(1, 0, t + 1, VMCNT(4), VMCNT(4), true, false);
    }
    GSTEP(0, 1, 14, VMCNT(4), VMCNT(4), true,  false);
    GSTEP(1, 0, 15, VMCNT(2), VMCNT(0), false, true);

    // ---- epilogue: tanh + pack into 16-chunk LDS image, then stream out.
    // acc[i][j]: k2 rows base = MT*256 + (i>>1)*128 + wm + (i&1)*32 (regs),
    //            m cols = NT*256 + j*128 + sB*32 + (lane&31) (lanes).
    // LDS image order: [mg = j (2)][k2 chunk kc (8)][4096 u16 chunk].
    const int mloc = lane & 31, hi = lane >> 5;
    unsigned int* stg32 = (unsigned int*)&lds[0][0][0];
#pragma unroll
    for (int i = 0; i < 4; i++) {
        const int kc  = (i >> 1) * 4 + sA + (i & 1);   // 0..7, disjoint per wm
        const int k2b = MT * 256 + (i >> 1) * 128 + wm + (i & 1) * 32;
#pragma unroll
        for (int j = 0; j < 2; j++) {
#pragma unroll
            for (int c = 0; c < 8; c++) {
                // regs 2c,2c+1 hold k2 rows n1off, n1off+1
                const int n1off = 8 * (c >> 1) + 4 * hi + 2 * (c & 1);
                const int n1g = k2b + n1off;
                float t0 = tanh_fast(s1v[n1g]     * acc[i][j][2 * c]     + b1v[n1g]);
                float t1 = tanh_fast(s1v[n1g + 1] * acc[i][j][2 * c + 1] + b1v[n1g + 1]);
                unsigned int pw = (unsigned int)f2bf(t0)
                                | ((unsigned int)f2bf(t1) << 16);
                const int a32 = (j * 8 + kc) * 2048 + sB * 512
                              + ((c >> 2) & 1) * 256 + ((c >> 1) & 1) * 128
                              + mloc * 4 + 2 * hi + (c & 1);
                stg32[a32] = pw;
            }
        }
    }
    __syncthreads();

    // stream out: per m-group, 8 contiguous chunks = 64 KB = 4096 uint4,
    // image group mg starts at mg*4096 uint4. 8 iters x 512 thr x 16 B.
#pragma unroll
    for (int mg = 0; mg < 2; mg++) {
        uint4* dst = (uint4*)(Hq + ((size_t)(2 * NT + mg) * 512 + MT * 8) * 4096);
        const uint4* src = (const uint4*)&lds[0][0][0];
#pragma unroll
        for (int it = 0; it < 8; it++)
            dst[it * 512 + tid] = src[mg * 4096 + it * 512 + tid];
    }
}

// ---------------------------------------------------------------------------
// GEMM2 (256^2, round-2 verified): out[m][n] = s2[n]*acc + b2[n]
// ---------------------------------------------------------------------------
__global__ __launch_bounds__(512, 2) void gemm2_256_kernel(
    const unsigned short* __restrict__ Ap,   // hq  chunks [mt128][k2t=512]
    const unsigned short* __restrict__ Bp,   // w2q chunks [nt128][k2t=512]
    float* __restrict__ out,
    const float* __restrict__ s2, const float* __restrict__ b2,
    int nstep)                                // K / 64 = 256
{
    __shared__ unsigned short lds[2][4][8192];   // 128 KiB
    const int tid = threadIdx.x;
    const int lane = tid & 63, wave = tid >> 6;
    const int NT = blockIdx.x, MT = blockIdx.y;
    const int wm = ((wave >> 2) & 1) * 64;
    const int sA = wm >> 5;
    const int sB = wave & 3;

    f32x16 acc[4][2] = {};

    const unsigned short* Ab = Ap + ((size_t)(2 * MT) * 512) * 4096;
    const unsigned short* Bb = Bp + ((size_t)(2 * NT) * 512) * 4096;

    auto STAGE = [&](int q, int half, int t) {
        const unsigned short* g = (half < 2)
            ? (Ab + ((size_t)(half * 512 + 2 * t)) * 4096)
            : (Bb + ((size_t)((half - 2) * 512 + 2 * t)) * 4096);
        unsigned short* l = &lds[q][half][0];
        gload_lds16(g + tid * 8,        l + tid * 8);
        gload_lds16(g + 4096 + tid * 8, l + 4096 + tid * 8);
    };

    bf16x8 fa0[4], fa1[4], fb0[4], fb1[4];

    STAGE(0, 0, 0); STAGE(0, 2, 0); STAGE(0, 3, 0); STAGE(0, 1, 0);
    VMCNT(4);
    BARRIER();

    for (int t = 0; t < nstep - 2; t += 2) {
        GSTEP(0, 1, t,     VMCNT(4), VMCNT(4), true, false);
        GSTEP(1, 0, t + 1, VMCNT(4), VMCNT(4), true, false);
    }
    GSTEP(0, 1, nstep - 2, VMCNT(4), VMCNT(4), true,  false);
    GSTEP(1, 0, nstep - 1, VMCNT(2), VMCNT(0), false, true);

    const int l31 = lane & 31;
    const int rowb = 4 * (lane >> 5);
#pragma unroll
    for (int j = 0; j < 2; j++) {
        int n = NT * 256 + j * 128 + sB * 32 + l31;
        float sc = s2[n], bb = b2[n];
#pragma unroll
        for (int i = 0; i < 4; i++) {
            int mbase = MT * 256 + (i >> 1) * 128 + wm + (i & 1) * 32;
#pragma unroll
            for (int reg = 0; reg < 16; reg++) {
                int m = mbase + (reg & 3) + 8 * (reg >> 2) + rowb;
                out[(size_t)m * 3072 + n] = sc * acc[i][j][reg] + bb;
            }
        }
    }
}

// ---------------------------------------------------------------------------
extern "C" void kernel_launch(void* const* d_in, const int* in_sizes, int n_in,
                              void* d_out, int out_size, void* d_ws, size_t ws_size,
                              hipStream_t stream) {
    const float* x  = (const float*)d_in[0];   // [4096,1024]
    const float* w1 = (const float*)d_in[1];   // [1024,16384]
    const float* s1 = (const float*)d_in[2];   // [16384]
    const float* b1 = (const float*)d_in[3];   // [16384]
    const float* w2 = (const float*)d_in[4];   // [16384,3072]
    const float* s2 = (const float*)d_in[5];   // [3072]
    const float* b2 = (const float*)d_in[6];   // [3072]
    const float* n1 = (const float*)d_in[7];   // [1024,16384]
    const float* n2 = (const float*)d_in[8];   // [16384,3072]
    const void* scale_p = d_in[9];             // scalar
    float* out = (float*)d_out;

    // workspace layout (MiB offsets): xq 8 | w1q 32 | hq 128 | w2q 96 = 264
    if (ws_size < (264ull << 20)) return;
    unsigned char* ws = (unsigned char*)d_ws;
    unsigned short* xq  = (unsigned short*)(ws);
    unsigned short* w1q = (unsigned short*)(ws + (8ull << 20));
    unsigned short* hq  = (unsigned short*)(ws + (40ull << 20));
    unsigned short* w2q = (unsigned short*)(ws + (168ull << 20));

    // pack/quant
    pack_x_kernel<<<dim3(32, 32), 256, 0, stream>>>(x, xq);
    quant_pack_w<<<dim3(32, 128), 256, 0, stream>>>(w1, n1, scale_p, w1q, 16384, 32);
    quant_pack_w<<<dim3(512, 24), 256, 0, stream>>>(w2, n2, scale_p, w2q, 3072, 512);

    // GEMM1 (256^2 swapped): w1^T[16384x1024] @ x^T[1024x4096] -> hq chunks
    gemm1_256_kernel<<<dim3(16, 64), 512, 0, stream>>>(w1q, xq, hq, s1, b1);
    // GEMM2: [4096x16384] @ [16384x3072] -> out fp32, 256^2 pipelined
    gemm2_256_kernel<<<dim3(12, 16), 512, 0, stream>>>(hq, w2q, out, s2, b2, 256);
}